// Round 4
// baseline (59.524 us; speedup 1.0000x reference)
//
#include <hip/hip_runtime.h>

// SecondOrderFeatureInteraction: B=16384, F=27, D=128 fp32.
// out[b, p] = dot(X[b,r], X[b,c]) for (r,c) = tril_indices(27, k=-1), p = r(r-1)/2 + c.
// Memory-bound (291 MB total traffic -> ~46 us floor at 6.3 TB/s).
//
// Design:
//  - 1 batch per block, 128 threads (2 waves), 16 KB LDS.
//  - LDS layout is TRANSPOSED [d][f] with stride 32 floats and an XOR swizzle
//    on the f-quad: element (f,d) lives at dword  d*32 + 4*((f>>2) ^ (d&7)) + (f&3).
//    * compute reads (ds_read_b128 of 4 features at one d): <=2-way bank conflict (free)
//    * staging scalar ds_writes: exactly 2 lanes/bank (free)
//  - Compute: wave 0 lanes 0..55; lane = 2*tile + dhalf. 28 lower-tri 4x4 tiles
//    of the 7x7 feature-quad grid; each lane does 64 d's: 2 ds_read_b128 + 16 FMA
//    (outer product), i.e. 0.5 LDS-floats per FMA -> LDS pipe below HBM floor.
//  - shfl_xor(1) combines the two d-halves; even lanes store the valid pairs.

#define SOI_F     27
#define SOI_D     128
#define SOI_NPAIR 351   // 27*26/2

__global__ __launch_bounds__(128, 4)
void soi_kernel(const float* __restrict__ in, float* __restrict__ out) {
    __shared__ float lds[SOI_D * 32];   // [d][f swizzled], 16 KB

    const int b    = blockIdx.x;
    const int tid  = threadIdx.x;
    const int w    = tid >> 6;          // wave 0..1
    const int lane = tid & 63;

    // ---------------- stage: global X[b][f][d] -> LDS [d][f] (swizzled) ----------------
    {
        const int f = w * 16 + (lane >> 2);     // wave0: f 0..15, wave1: f 16..31
        if (f < SOI_F) {
            const float4* in4 = reinterpret_cast<const float4*>(in)
                              + (size_t)b * (SOI_F * SOI_D / 4) + f * (SOI_D / 4);
            const int fq = f >> 2, fl = f & 3;
            #pragma unroll
            for (int it = 0; it < 8; ++it) {
                const int c4 = (lane & 3) + 4 * it;         // float4 chunk within the row
                const float4 v = in4[c4];                   // 64B-contiguous per 4 lanes
                const float vv[4] = {v.x, v.y, v.z, v.w};
                #pragma unroll
                for (int k = 0; k < 4; ++k) {
                    const int d = 4 * c4 + k;
                    lds[d * 32 + 4 * (fq ^ (d & 7)) + fl] = vv[k];
                }
            }
        }
    }
    __syncthreads();

    // ---------------- compute: wave 0, lanes 0..55 ----------------
    if (tid >= 56) return;

    const int tile  = lane >> 1;    // 0..27: lower-tri (incl diag) tile of 7x7 quad grid
    const int dhalf = lane & 1;     // d in [0,64) or [64,128)

    int ti = 0;                                         // tile -> (ti, tj), ti >= tj
    while ((ti + 1) * (ti + 2) / 2 <= tile) ++ti;
    const int tj = tile - ti * (ti + 1) / 2;

    float acc[4][4];
    #pragma unroll
    for (int a = 0; a < 4; ++a)
        #pragma unroll
        for (int q = 0; q < 4; ++q) acc[a][q] = 0.0f;

    const float* ldsb = lds + dhalf * 64 * 32;
    #pragma unroll 8
    for (int c = 0; c < 64; ++c) {
        const int s = c & 7;        // (dhalf*64 + c) & 7 == c & 7
        const float4 vi = *reinterpret_cast<const float4*>(ldsb + c * 32 + 4 * (ti ^ s));
        const float4 vj = *reinterpret_cast<const float4*>(ldsb + c * 32 + 4 * (tj ^ s));
        const float ai[4] = {vi.x, vi.y, vi.z, vi.w};
        const float bj[4] = {vj.x, vj.y, vj.z, vj.w};
        #pragma unroll
        for (int a = 0; a < 4; ++a)
            #pragma unroll
            for (int q = 0; q < 4; ++q)
                acc[a][q] += ai[a] * bj[q];
    }

    // combine the two d-halves (partner lanes 2t / 2t+1, both active)
    #pragma unroll
    for (int a = 0; a < 4; ++a)
        #pragma unroll
        for (int q = 0; q < 4; ++q)
            acc[a][q] += __shfl_xor(acc[a][q], 1, 64);

    // ---------------- store: even lanes write valid pairs ----------------
    if (dhalf == 0) {
        float* outb = out + (size_t)b * SOI_NPAIR;
        #pragma unroll
        for (int a = 0; a < 4; ++a) {
            const int i = 4 * ti + a;                   // larger feature index (row r)
            if (i < SOI_F) {
                const int pbase = i * (i - 1) / 2;
                #pragma unroll
                for (int q = 0; q < 4; ++q) {
                    const int j = 4 * tj + q;           // smaller feature index (col c)
                    if (j < i) outb[pbase + j] = acc[a][q];
                }
            }
        }
    }
}

extern "C" void kernel_launch(void* const* d_in, const int* in_sizes, int n_in,
                              void* d_out, int out_size, void* d_ws, size_t ws_size,
                              hipStream_t stream) {
    const float* in  = (const float*)d_in[0];
    float*       out = (float*)d_out;
    const int B = in_sizes[0] / (SOI_F * SOI_D);    // 16384
    soi_kernel<<<dim3(B), dim3(128), 0, stream>>>(in, out);
}

// Round 5
// 58.340 us; speedup vs baseline: 1.0203x; 1.0203x over previous
//
#include <hip/hip_runtime.h>

// SecondOrderFeatureInteraction: B=16384, F=27, D=128 fp32.
// out[b, p] = dot(X[b,r], X[b,c]) for (r,c) = tril_indices(27, k=-1), p = r(r-1)/2 + c.
// Memory-bound: 268 MB read + 23 MB write -> ~46 us floor at 6.3 TB/s achievable.
// R4 measured 59.5 us (4.9 TB/s effective). R5 change: coalesced LDS-staged output
// (scattered predicated dword stores -> contiguous nontemporal stores, ~300 -> ~18
// write transactions/block, kills any RFO on partial lines).
//
// Design:
//  - 1 batch per block, 128 threads (2 waves), 16 KB LDS (10 blocks/CU).
//  - LDS layout TRANSPOSED [d][f], stride 32 floats, XOR swizzle on the f-quad:
//    element (f,d) at dword  d*32 + 4*((f>>2) ^ (d&7)) + (f&3).
//    compute ds_read_b128: <=2-way conflict (free, m136); staging ds_write_b32:
//    exactly 2 lanes/bank (free).
//  - Compute: wave 0 lanes 0..55; lane = 2*tile + dhalf; 28 lower-tri 4x4 tiles of
//    the 7x7 feature-quad grid; 64 d-iters of {2 ds_read_b128 + 16 fp32 FMA}.
//  - shfl_xor(1) combines d-halves; even lanes stage results into LDS; all 128
//    threads store the 351-dword slice contiguously (nontemporal).

#define SOI_F     27
#define SOI_D     128
#define SOI_NPAIR 351   // 27*26/2

__global__ __launch_bounds__(128, 4)
void soi_kernel(const float* __restrict__ in, float* __restrict__ out) {
    __shared__ float lds[SOI_D * 32];   // [d][f swizzled], 16 KB; reused as out-stage

    const int b    = blockIdx.x;
    const int tid  = threadIdx.x;
    const int w    = tid >> 6;          // wave 0..1
    const int lane = tid & 63;

    // ---------------- stage: global X[b][f][d] -> LDS [d][f] (swizzled) ----------------
    {
        const int f = w * 16 + (lane >> 2);     // wave0: f 0..15, wave1: f 16..31
        if (f < SOI_F) {
            const float4* in4 = reinterpret_cast<const float4*>(in)
                              + (size_t)b * (SOI_F * SOI_D / 4) + f * (SOI_D / 4);
            const int fq = f >> 2, fl = f & 3;
            #pragma unroll
            for (int it = 0; it < 8; ++it) {
                const int c4 = (lane & 3) + 4 * it;         // float4 chunk within the row
                const float4 v = in4[c4];                   // 64B-contiguous per 4 lanes
                const float vv[4] = {v.x, v.y, v.z, v.w};
                #pragma unroll
                for (int k = 0; k < 4; ++k) {
                    const int d = 4 * c4 + k;
                    lds[d * 32 + 4 * (fq ^ (d & 7)) + fl] = vv[k];
                }
            }
        }
    }
    __syncthreads();

    // ---------------- compute: wave 0, lanes 0..55 ----------------
    float acc[4][4];
    int ti = 0, tj = 0;
    if (tid < 56) {
        const int tile  = lane >> 1;    // 0..27: lower-tri (incl diag) tile of 7x7 quads
        const int dhalf = lane & 1;     // d in [0,64) or [64,128)

        while ((ti + 1) * (ti + 2) / 2 <= tile) ++ti;   // tile -> (ti, tj), ti >= tj
        tj = tile - ti * (ti + 1) / 2;

        #pragma unroll
        for (int a = 0; a < 4; ++a)
            #pragma unroll
            for (int q = 0; q < 4; ++q) acc[a][q] = 0.0f;

        const float* ldsb = lds + dhalf * 64 * 32;
        #pragma unroll 8
        for (int c = 0; c < 64; ++c) {
            const int s = c & 7;        // (dhalf*64 + c) & 7 == c & 7
            const float4 vi = *reinterpret_cast<const float4*>(ldsb + c * 32 + 4 * (ti ^ s));
            const float4 vj = *reinterpret_cast<const float4*>(ldsb + c * 32 + 4 * (tj ^ s));
            const float ai[4] = {vi.x, vi.y, vi.z, vi.w};
            const float bj[4] = {vj.x, vj.y, vj.z, vj.w};
            #pragma unroll
            for (int a = 0; a < 4; ++a)
                #pragma unroll
                for (int q = 0; q < 4; ++q)
                    acc[a][q] += ai[a] * bj[q];
        }

        // combine the two d-halves (partner lanes 2t / 2t+1, both active)
        #pragma unroll
        for (int a = 0; a < 4; ++a)
            #pragma unroll
            for (int q = 0; q < 4; ++q)
                acc[a][q] += __shfl_xor(acc[a][q], 1, 64);
    }

    __syncthreads();    // all compute-phase LDS reads complete before reuse

    // ---------------- stage results into LDS (even compute lanes) ----------------
    if (tid < 56 && (tid & 1) == 0) {
        #pragma unroll
        for (int a = 0; a < 4; ++a) {
            const int i = 4 * ti + a;                   // larger feature index (row r)
            if (i < SOI_F) {
                const int pbase = i * (i - 1) / 2;
                #pragma unroll
                for (int q = 0; q < 4; ++q) {
                    const int j = 4 * tj + q;           // smaller feature index (col c)
                    if (j < i) lds[pbase + j] = acc[a][q];
                }
            }
        }
    }
    __syncthreads();

    // ---------------- store: contiguous, all 128 threads, nontemporal ----------------
    float* outb = out + (size_t)b * SOI_NPAIR;
    #pragma unroll
    for (int t = tid; t < SOI_NPAIR; t += 128)
        __builtin_nontemporal_store(lds[t], &outb[t]);
}

extern "C" void kernel_launch(void* const* d_in, const int* in_sizes, int n_in,
                              void* d_out, int out_size, void* d_ws, size_t ws_size,
                              hipStream_t stream) {
    const float* in  = (const float*)d_in[0];
    float*       out = (float*)d_out;
    const int B = in_sizes[0] / (SOI_F * SOI_D);    // 16384
    soi_kernel<<<dim3(B), dim3(128), 0, stream>>>(in, out);
}

// Round 6
// 41.041 us; speedup vs baseline: 1.4504x; 1.4215x over previous
//
#include <hip/hip_runtime.h>

// SecondOrderFeatureInteraction: B=16384, F=27, D=128 fp32.
// out[b, p] = dot(X[b,r], X[b,c]) for (r,c) = tril_indices(27, k=-1), p = r(r-1)/2 + c.
// HBM floor: 268 MB read + 23 MB write -> ~46 us at 6.3 TB/s.
// R5 (VALU outer-product) = 58.3 us: LDS read pipe (~40 us) + HBM (~46 us) co-bound.
// R6: bf16 MFMA Gram trick. G = X.X^T is one 32x32x(K=128) MFMA chain per batch.
//  - For a Gram matrix, the CDNA B-frag layout (col=lane&31, k=8*(lane>>5)+j) mirrors
//    the A-frag (row=lane&31), so ONE ds_read_b128 per k-window serves BOTH operands:
//    acc = mfma(frag, frag, acc). k-permutation-invariant; G symmetric -> transpose-immune.
//  - 1 wave = 1 batch, 4 waves/block, 8 KB LDS/wave, NO barriers (wave-private LDS).
//  - LDS: [f:32 rows][256 B] bf16, 16B-slot XOR swizzle slot=(w&7)^(f&7) -> 2-way max
//    (free, m136) on both ds_write_b64 staging and ds_read_b128 frag reads.
//  - Rows 27..31 are never written: garbage only reaches C rows/cols >= 27, never read.
//  - C layout (HW-verified m74/m101): col=lane&31, row=(reg&3)+8*(reg>>2)+4*(lane>>5).
//  - Lower-tri staged into LDS, then contiguous nontemporal store (R5's write path).

#define SOI_F     27
#define SOI_D     128
#define SOI_NPAIR 351   // 27*26/2

typedef __attribute__((ext_vector_type(8)))  short bf16x8;
typedef __attribute__((ext_vector_type(16))) float f32x16;

__device__ __forceinline__ unsigned pack2bf(float a, float b) {
    // round-to-nearest-even f32 -> bf16, packed pair
    unsigned ua = __float_as_uint(a), ub = __float_as_uint(b);
    ua += 0x7fffu + ((ua >> 16) & 1u);
    ub += 0x7fffu + ((ub >> 16) & 1u);
    return (ua >> 16) | (ub & 0xffff0000u);
}

__global__ __launch_bounds__(256, 4)
void soi_kernel(const float* __restrict__ in, float* __restrict__ out) {
    __shared__ unsigned lds[4][2048];          // 8 KB per wave (= per batch)
    const int tid = threadIdx.x;
    const int wv  = tid >> 6;
    const int l   = tid & 63;
    const int b   = blockIdx.x * 4 + wv;
    unsigned* L = lds[wv];

    // ---- stage: global fp32 -> bf16 LDS (864 float4s = 14 coalesced 1KB instrs) ----
    {
        const float4* in4 = reinterpret_cast<const float4*>(in) + (size_t)b * 864;
        #pragma unroll
        for (int it = 0; it < 14; ++it) {
            const int g4 = l + 64 * it;
            if (g4 < 864) {
                const float4 v = in4[g4];
                const int g = g4 << 2;              // flat element index
                const int f = g >> 7;               // feature row 0..26
                const int d = g & 127;              // d, multiple of 4
                const int w = d >> 3;               // 16B slot index within row (0..15)
                const int dw = (f << 6) + ((w >> 3) << 5)
                             + (((w & 7) ^ (f & 7)) << 2) + ((d & 7) >> 1);
                uint2 pk;
                pk.x = pack2bf(v.x, v.y);
                pk.y = pack2bf(v.z, v.w);
                *reinterpret_cast<uint2*>(&L[dw]) = pk;   // ds_write_b64, 2-way max
            }
        }
    }
    // No __syncthreads: LDS regions are wave-private and per-wave DS ops are in-order.

    // ---- compute: 8x mfma_f32_32x32x16_bf16, frag used as BOTH A and B ----
    const int f = l & 31, h = l >> 5;
    f32x16 acc = {0,0,0,0,0,0,0,0,0,0,0,0,0,0,0,0};
    #pragma unroll
    for (int m = 0; m < 8; ++m) {
        const int w  = 2 * m + h;                  // k-window: k0 = 16m + 8h
        const int dw = (f << 6) + ((w >> 3) << 5) + (((w & 7) ^ (f & 7)) << 2);
        const bf16x8 frag = *reinterpret_cast<const bf16x8*>(&L[dw]);  // ds_read_b128
        acc = __builtin_amdgcn_mfma_f32_32x32x16_bf16(frag, frag, acc, 0, 0, 0);
    }

    // ---- extract lower triangle into LDS (reuse region; data-dep orders vs reads) ----
    #pragma unroll
    for (int reg = 0; reg < 16; ++reg) {
        const int r = (reg & 3) + 8 * (reg >> 2) + (h << 2);   // C row
        if (r < SOI_F && f < r) {                              // f = C col
            const int p = ((r * (r - 1)) >> 1) + f;
            L[p] = __float_as_uint(acc[reg]);
        }
    }

    // ---- contiguous nontemporal store of the 351-dword batch slice ----
    float* outb = out + (size_t)b * SOI_NPAIR;
    #pragma unroll
    for (int it = 0; it < 6; ++it) {
        const int idx = l + 64 * it;
        if (idx < SOI_NPAIR)
            __builtin_nontemporal_store(__uint_as_float(L[idx]), &outb[idx]);
    }
}

extern "C" void kernel_launch(void* const* d_in, const int* in_sizes, int n_in,
                              void* d_out, int out_size, void* d_ws, size_t ws_size,
                              hipStream_t stream) {
    const float* in  = (const float*)d_in[0];
    float*       out = (float*)d_out;
    const int B = in_sizes[0] / (SOI_F * SOI_D);    // 16384, divisible by 4
    soi_kernel<<<dim3(B / 4), dim3(256), 0, stream>>>(in, out);
}